// Round 1
// baseline (928.243 us; speedup 1.0000x reference)
//
#include <hip/hip_runtime.h>
#include <hip/hip_bf16.h>
#include <string.h>

typedef unsigned short u16;
typedef __attribute__((ext_vector_type(8))) short short8;
typedef __attribute__((ext_vector_type(4))) float floatx4;
typedef __attribute__((ext_vector_type(4))) unsigned short ushort4v;
typedef __attribute__((ext_vector_type(8))) unsigned short ushort8v;

#define NWIN 2048
#define NTOK 49
#define NH 16
#define HDIM 32
#define CDIM 512
#define MTOT (NWIN * NTOK)   /* 100352 */
#define NOUT (3 * CDIM)      /* 1536 */
#define KDIM CDIM            /* 512 */

__device__ inline float b2f(u16 u) {
    unsigned int x = ((unsigned int)u) << 16;
    float f; __builtin_memcpy(&f, &x, 4); return f;
}
__device__ inline u16 f2b(float f) {
    unsigned int u; __builtin_memcpy(&u, &f, 4);
    unsigned int r = (u + 0x7fffu + ((u >> 16) & 1u)) >> 16;
    return (u16)r;
}
__device__ inline void gload16(const void* g, void* l) {
    __builtin_amdgcn_global_load_lds((const __attribute__((address_space(1))) unsigned int*)g,
                                     (__attribute__((address_space(3))) unsigned int*)l, 16, 0, 0);
}

// ---------------- prep: fp32 -> bf16 convert of hidden_states ----------------
__global__ void k_cvt_x(const float4* __restrict__ x, ushort4v* __restrict__ xb, int n4) {
    int i = blockIdx.x * blockDim.x + threadIdx.x;
    int stride = gridDim.x * blockDim.x;
    for (; i < n4; i += stride) {
        float4 v = x[i];
        ushort4v o = { f2b(v.x), f2b(v.y), f2b(v.z), f2b(v.w) };
        xb[i] = o;
    }
}

// ---------------- prep: pack Wqkv (bf16 [1536,512]) + bias (fp32 [1536]) -----
__global__ void k_pack_w(const float* __restrict__ wq, const float* __restrict__ wk,
                         const float* __restrict__ wv, const float* __restrict__ bq,
                         const float* __restrict__ bk, const float* __restrict__ bv,
                         u16* __restrict__ wout, float* __restrict__ bout) {
    const int WN = CDIM * CDIM; // 262144
    int i = blockIdx.x * blockDim.x + threadIdx.x;
    if (i < 3 * WN) {
        const float* src = (i < WN) ? wq : (i < 2 * WN ? wk : wv);
        wout[i] = f2b(src[i & (WN - 1)]);
    }
    if (i < 3 * CDIM) {
        const float* sb = (i < CDIM) ? bq : (i < 2 * CDIM ? bk : bv);
        bout[i] = sb[i & (CDIM - 1)];
    }
}

// ---------------- prep: bias+mask table bm[w][h][i][j], 64*16*49*49 ----------
__global__ void k_bm(const float* __restrict__ mask, const float* __restrict__ bt,
                     float* __restrict__ bm) {
    int t = blockIdx.x;          // 0..1023
    int w = t >> 4, h = t & 15;
    for (int e = threadIdx.x; e < NTOK * NTOK; e += blockDim.x) {
        int i = e / 49, j = e - i * 49;
        int ri = i / 7, ci = i - ri * 7;
        int rj = j / 7, cj = j - rj * 7;
        int idx = (ri - rj + 6) * 13 + (ci - cj + 6);
        bm[(size_t)t * 2401 + e] = bt[idx * 16 + h] + mask[(size_t)w * 2401 + e];
    }
}

// ---------------- QKV projection GEMM: [100352,512] x [1536,512]^T -----------
// 128x128 tile, BK=32, 4 waves (2x2 of 64x64), global_load_lds w16,
// XOR-swizzled LDS chunks so ds_read_b128 fragment reads are 2-way (free).
__global__ __launch_bounds__(256)
void k_gemm(const u16* __restrict__ A, const u16* __restrict__ Bw,
            const float* __restrict__ bias, u16* __restrict__ C) {
    __shared__ __align__(16) u16 As[128 * 32];
    __shared__ __align__(16) u16 Bs[128 * 32];
    const int tid = threadIdx.x;
    const int lane = tid & 63;
    const int wave = tid >> 6;
    const int n0 = blockIdx.x * 128;   // x fastest: 12 n-tiles share an A-tile in L2
    const int m0 = blockIdx.y * 128;
    const int mh = (wave & 1) * 64;
    const int nh = (wave >> 1) * 64;

    floatx4 acc[4][4];
#pragma unroll
    for (int mi = 0; mi < 4; mi++)
#pragma unroll
        for (int ni = 0; ni < 4; ni++)
            acc[mi][ni] = (floatx4){0.f, 0.f, 0.f, 0.f};

    // staging: 512 x 16B per tile per matrix; thread does i and i+256
    const int rA1 = tid >> 2, c1 = tid & 3;
    const int rA2 = rA1 + 64;
    const int cg1 = c1 ^ ((rA1 >> 1) & 3);
    const int cg2 = c1 ^ ((rA2 >> 1) & 3);
    const u16* pa1 = A + (size_t)(m0 + rA1) * KDIM + cg1 * 8;
    const u16* pa2 = A + (size_t)(m0 + rA2) * KDIM + cg2 * 8;
    const u16* pb1 = Bw + (size_t)(n0 + rA1) * KDIM + cg1 * 8;
    const u16* pb2 = Bw + (size_t)(n0 + rA2) * KDIM + cg2 * 8;
    u16* la1 = &As[tid * 8];
    u16* la2 = &As[(tid + 256) * 8];
    u16* lb1 = &Bs[tid * 8];
    u16* lb2 = &Bs[(tid + 256) * 8];

    // fragment LDS offsets (elements): row r, chunk = quad ^ ((r>>1)&3)
    int aoff[4], boff[4];
    const int quad = lane >> 4;
#pragma unroll
    for (int mi = 0; mi < 4; mi++) {
        int r = mh + mi * 16 + (lane & 15);
        aoff[mi] = r * 32 + (quad ^ ((r >> 1) & 3)) * 8;
        int rn = nh + mi * 16 + (lane & 15);
        boff[mi] = rn * 32 + (quad ^ ((rn >> 1) & 3)) * 8;
    }

    for (int ks = 0; ks < 16; ++ks) {
        const int k0 = ks * 32;
        gload16(pa1 + k0, la1);
        gload16(pa2 + k0, la2);
        gload16(pb1 + k0, lb1);
        gload16(pb2 + k0, lb2);
        __syncthreads();
        short8 af[4], bf[4];
#pragma unroll
        for (int mi = 0; mi < 4; mi++) af[mi] = *(const short8*)&As[aoff[mi]];
#pragma unroll
        for (int ni = 0; ni < 4; ni++) bf[ni] = *(const short8*)&Bs[boff[ni]];
#pragma unroll
        for (int mi = 0; mi < 4; mi++)
#pragma unroll
            for (int ni = 0; ni < 4; ni++)
                acc[mi][ni] = __builtin_amdgcn_mfma_f32_16x16x32_bf16(af[mi], bf[ni], acc[mi][ni], 0, 0, 0);
        __syncthreads();
    }

    // epilogue: D row=(quad*4+r), col=(lane&15); add bias, store bf16
    const int colc = lane & 15;
#pragma unroll
    for (int ni = 0; ni < 4; ni++) {
        int gn = n0 + nh + ni * 16 + colc;
        float bv_ = bias[gn];
#pragma unroll
        for (int mi = 0; mi < 4; mi++) {
            size_t gmb = (size_t)(m0 + mh + mi * 16 + quad * 4);
#pragma unroll
            for (int r = 0; r < 4; r++)
                C[(gmb + r) * NOUT + gn] = f2b(acc[mi][ni][r] + bv_);
        }
    }
}

// ---------------- attention: one wave per (window b, head h) -----------------
__global__ __launch_bounds__(256)
void k_attn(const u16* __restrict__ qkv, const float* __restrict__ bm,
            float* __restrict__ out) {
    __shared__ __align__(16) float kvb[4][2][NTOK * HDIM]; // per-wave K,V fp32
    const int lane = threadIdx.x & 63;
    const int wave = threadIdx.x >> 6;
    const int task = blockIdx.x * 4 + wave;  // 0..32767
    const int b = task >> 4;
    const int h = task & 15;
    float* Ks = kvb[wave][0];
    float* Vs = kvb[wave][1];

    const size_t rowbase = (size_t)b * NTOK * NOUT;
    // stage K,V (bf16 -> fp32) into LDS, 8B granules
    for (int i = lane; i < 392; i += 64) {
        int n = i >> 3;
        int dq = (i & 7) * 4;
        const u16* kp = qkv + rowbase + (size_t)n * NOUT + 512 + h * 32 + dq;
        ushort4v kk = *(const ushort4v*)kp;
        ushort4v vv = *(const ushort4v*)(kp + 512);
#pragma unroll
        for (int z = 0; z < 4; z++) {
            Ks[n * 32 + dq + z] = b2f(kk[z]);
            Vs[n * 32 + dq + z] = b2f(vv[z]);
        }
    }
    // Q row for this lane into registers
    const int irow = lane < 49 ? lane : 48;
    float q[32];
    {
        const u16* qp = qkv + rowbase + (size_t)irow * NOUT + h * 32;
#pragma unroll
        for (int c = 0; c < 4; c++) {
            ushort8v qq = *(const ushort8v*)(qp + c * 8);
#pragma unroll
            for (int z = 0; z < 8; z++) q[c * 8 + z] = b2f(qq[z]);
        }
    }
    __syncthreads();

    // scores row (in-lane), +bias+mask
    const float* bmr = bm + ((size_t)((b & 63) * 16 + h)) * 2401 + irow * 49;
    float s[49];
#pragma unroll
    for (int j = 0; j < 49; j++) {
        const floatx4* kr = (const floatx4*)(Ks + j * 32);
        float a0 = 0.f, a1 = 0.f, a2 = 0.f, a3 = 0.f;
#pragma unroll
        for (int dq = 0; dq < 8; dq++) {
            floatx4 kv = kr[dq];
            a0 += q[dq * 4 + 0] * kv[0];
            a1 += q[dq * 4 + 1] * kv[1];
            a2 += q[dq * 4 + 2] * kv[2];
            a3 += q[dq * 4 + 3] * kv[3];
        }
        s[j] = (a0 + a1 + a2 + a3) * 0.17677669529663687f + bmr[j];
    }
    // in-lane softmax
    float mx = s[0];
#pragma unroll
    for (int j = 1; j < 49; j++) mx = fmaxf(mx, s[j]);
    float sum = 0.f;
#pragma unroll
    for (int j = 0; j < 49; j++) { s[j] = __expf(s[j] - mx); sum += s[j]; }
    float inv = 1.0f / sum;
    // P @ V
    float o[32];
#pragma unroll
    for (int d = 0; d < 32; d++) o[d] = 0.f;
#pragma unroll
    for (int j = 0; j < 49; j++) {
        float pj = s[j];
        const floatx4* vr = (const floatx4*)(Vs + j * 32);
#pragma unroll
        for (int dq = 0; dq < 8; dq++) {
            floatx4 vv = vr[dq];
            o[dq * 4 + 0] += pj * vv[0];
            o[dq * 4 + 1] += pj * vv[1];
            o[dq * 4 + 2] += pj * vv[2];
            o[dq * 4 + 3] += pj * vv[3];
        }
    }
    if (lane < 49) {
        float* op = out + ((size_t)(b * 49 + lane)) * CDIM + h * 32;
#pragma unroll
        for (int dq = 0; dq < 8; dq++) {
            floatx4 res = { o[dq * 4 + 0] * inv, o[dq * 4 + 1] * inv,
                            o[dq * 4 + 2] * inv, o[dq * 4 + 3] * inv };
            *(floatx4*)(op + dq * 4) = res;
        }
    }
}

extern "C" void kernel_launch(void* const* d_in, const int* in_sizes, int n_in,
                              void* d_out, int out_size, void* d_ws, size_t ws_size,
                              hipStream_t stream) {
    const float* hs   = (const float*)d_in[0];
    const float* mask = (const float*)d_in[1];
    const float* wq   = (const float*)d_in[2];
    const float* bq   = (const float*)d_in[3];
    const float* wk   = (const float*)d_in[4];
    const float* bk   = (const float*)d_in[5];
    const float* wv   = (const float*)d_in[6];
    const float* bv   = (const float*)d_in[7];
    const float* bt   = (const float*)d_in[8];
    float* out = (float*)d_out;

    char* ws = (char*)d_ws;
    size_t off = 0;
    u16* xb = (u16*)(ws + off);      off += (size_t)MTOT * CDIM * 2;       // 102.8 MB
    u16* wb = (u16*)(ws + off);      off += (size_t)NOUT * KDIM * 2;       // 1.5 MB
    float* biasb = (float*)(ws + off); off += (size_t)NOUT * 4;
    off = (off + 255) & ~(size_t)255;
    float* bm = (float*)(ws + off);  off += (size_t)1024 * 2401 * 4;       // 9.8 MB
    off = (off + 255) & ~(size_t)255;
    u16* qkv = (u16*)(ws + off);     off += (size_t)MTOT * NOUT * 2;       // 308 MB

    k_cvt_x<<<4096, 256, 0, stream>>>((const float4*)hs, (ushort4v*)xb, MTOT * CDIM / 4);
    k_pack_w<<<3072, 256, 0, stream>>>(wq, wk, wv, bq, bk, bv, wb, biasb);
    k_bm<<<1024, 256, 0, stream>>>(mask, bt, bm);
    k_gemm<<<dim3(12, 784), 256, 0, stream>>>(xb, wb, biasb, qkv);
    k_attn<<<8192, 256, 0, stream>>>(qkv, bm, out);
}